// Round 6
// baseline (393.933 us; speedup 1.0000x reference)
//
#include <hip/hip_runtime.h>
#include <hip/hip_bf16.h>

// Problem constants (fixed by reference setup_inputs):
//   K3=27, PAIRS_PER_K=131072 (=2^17), N_VOX=262144 (=2^18), C_IN=C_OUT=32
//   M = 3,538,944 pairs. out = [262144][32] fp32.
//
// History: R1 113M fp32 atomics = 5.9ms. R2 per-thread LDS W = 3x FMA floor.
// R3 scalar gather latency-bound. R4 MFMA gather 312us. R5 dist-4 prefetch
// regressed. R6 runtime-indexed private arrays -> scratch. RULE: no
// runtime-indexed private arrays. R7 split-k 497us (gather 296, 48 VGPR).
// R8 560us: T2 round works but hi+lo W -> VGPR 108, occ 22% -> flat;
// one-pass atomic-return claim loses to 2-pass; W-lo numerically no-op.
// R9 642us: forced min-waves -> VGPR 40, WRITE_SIZE 732MB scratch spill.
// RULES: never force min-waves beyond live set; WRITE_SIZE explosion =
// spill signature. R10 397us: T2 round at 64 VGPR / occ 43% + feat16 ->
// gather 154. R11 389us: probes-then-rows reorder -> gather 138 (VGPR
// still 64, WRITE 48MB); 2-pair claim neutral -> claim not MLP-starved
// at 2/thread.
// R12 (this): (a) ONE setup kernel replaces memset x2 + bf_prep +
// feat16_prep (range-partitioned grid, disjoint regions) — 4 dispatches
// -> 1; (b) claim passes 4 pairs/thread (tests MLP-bound vs L3-bound);
// (c) gather hoists round-0 probes + speculative ovf loads above the
// first barrier (overlap probe latency with staging; R10 had this, R11
// dropped it). Tripwire: WRITE_SIZE ~48MB, VGPR <= ~96.

#define N_VOX    262144
#define LOG2_NV  18
#define C_CH     32
#define K3       27
#define LOG2_PPK 17
#define BLOCK    256
#define FLAG_FIN 0x40000000
#define ECAP     4096
#define PLPAD    36   // plane row stride: rows differ by 36%32=4 -> 2-way max
#define FRAGN    (K3 * 2 * 64)   // uint4 fragments (hi-precision W only)
#define NF16     (N_VOX * 4)     // feat16 uint4 work items

typedef __attribute__((ext_vector_type(8))) short bf16x8;
typedef __attribute__((ext_vector_type(4))) float f32x4;

__device__ __forceinline__ unsigned short f2bf(float f) {
  union { __hip_bfloat16 h; unsigned short u; } cv;
  cv.h = __float2bfloat16(f);
  return cv.u;
}

// ---------------------------------------------------------------------------
// Setup: one kernel does all init. Work-id ranges (disjoint memory):
//   [0, nt4)            : clear T (+T2) to -1, int4 stores
//   [nt4, nt4+nc4)      : clear ovf_cnt + ecnt to 0
//   [.., +NF16 if use16): feat16 = bf16(in_feature), uint4 stores
//   [.., +FRAGN)        : Bf = W permuted to mfma B-operand lanes (m89/m91)
__global__ __launch_bounds__(BLOCK) void setup_kernel(
    int4* __restrict__ clrT, long nt4, int4* __restrict__ clrC, long nc4,
    const float* __restrict__ in_feature, unsigned short* __restrict__ feat16,
    int use16, const float* __restrict__ kernel_w,
    unsigned short* __restrict__ Bf) {
  long idx = (long)blockIdx.x * BLOCK + threadIdx.x;
  if (idx < nt4) {
    clrT[idx] = make_int4(-1, -1, -1, -1);
    return;
  }
  idx -= nt4;
  if (idx < nc4) {
    clrC[idx] = make_int4(0, 0, 0, 0);
    return;
  }
  idx -= nc4;
  if (use16) {
    if (idx < NF16) {
      const float4* src = (const float4*)in_feature + (idx << 1);
      float4 f0 = src[0], f1 = src[1];
      union { unsigned short u[8]; uint4 v; } pk;
      pk.u[0] = f2bf(f0.x); pk.u[1] = f2bf(f0.y);
      pk.u[2] = f2bf(f0.z); pk.u[3] = f2bf(f0.w);
      pk.u[4] = f2bf(f1.x); pk.u[5] = f2bf(f1.y);
      pk.u[6] = f2bf(f1.z); pk.u[7] = f2bf(f1.w);
      ((uint4*)feat16)[idx] = pk.v;
      return;
    }
    idx -= NF16;
  }
  if (idx < FRAGN) {
    int wid = (int)idx;
    int lane = wid & 63;
    int kc = wid >> 6;
    int k = kc >> 1, t = kc & 1;
    int i0 = (lane >> 4) * 8;
    int c = t * 16 + (lane & 15);
    union { unsigned short u[8]; uint4 v; } pk;
#pragma unroll
    for (int j = 0; j < 8; ++j)
      pk.u[j] = f2bf(kernel_w[(k << 10) + (i0 + j) * C_CH + c]);
    ((uint4*)Bf)[wid] = pk.v;
  }
}

// ---------------------------------------------------------------------------
// Pass A: last-writer-wins claim (plain stores, fire-and-forget).
// 4 pairs/thread: 2x int4 load, 4 independent random stores.
__global__ __launch_bounds__(BLOCK) void passA_kernel(
    const int4* __restrict__ nbmap2, int* __restrict__ T, int Mq) {
  int q = blockIdx.x * BLOCK + threadIdx.x;
  if (q >= Mq) return;
  int4 na = nbmap2[q * 2];
  int4 nb = nbmap2[q * 2 + 1];
  int p0 = q << 2, p1 = p0 | 1, p2 = p0 | 2, p3 = p0 | 3;
  T[((p0 >> LOG2_PPK) << LOG2_NV) + na.y] = p0;
  T[((p1 >> LOG2_PPK) << LOG2_NV) + na.w] = p1;
  T[((p2 >> LOG2_PPK) << LOG2_NV) + nb.y] = p2;
  T[((p3 >> LOG2_PPK) << LOG2_NV) + nb.w] = p3;
}

// Loser path: exch into T2 (one atomic, independent chains); displaced ->
// per-voxel overflow list; list overflow -> emergency list.
__device__ __forceinline__ void loser_path(
    int vox, int k, int in, int* __restrict__ T2, int idx, int use2,
    int* __restrict__ ovf_cnt, int* __restrict__ ovf, int S2,
    int* __restrict__ ecnt, int2* __restrict__ elist) {
  int val = in;
  if (use2) {
    val = atomicExch(&T2[idx], val);          // loser takes second slot
    if (val < 0) return;                      // first loser: done
  }
  int pos = atomicAdd(&ovf_cnt[vox], 1);
  if (pos < S2) {
    ovf[(pos << LOG2_NV) + vox] = (k << LOG2_NV) | val;
  } else {
    int ep = atomicAdd(ecnt, 1);
    if (ep < ECAP) elist[ep] = make_int2(vox, (k << LOG2_NV) | val);
  }
}

// Pass B: winners finalize (FLAG|in_idx, plain store); losers -> loser_path.
// 4 pairs/thread; all four T reads issued before any resolution (MLP).
__global__ __launch_bounds__(BLOCK) void passB_kernel(
    const int4* __restrict__ nbmap2, int* __restrict__ T, int* __restrict__ T2,
    int use2, int* __restrict__ ovf_cnt, int* __restrict__ ovf, int S2,
    int* __restrict__ ecnt, int2* __restrict__ elist, int Mq) {
  int q = blockIdx.x * BLOCK + threadIdx.x;
  if (q >= Mq) return;
  int4 na = nbmap2[q * 2];
  int4 nb = nbmap2[q * 2 + 1];
  int p0 = q << 2, p1 = p0 | 1, p2 = p0 | 2, p3 = p0 | 3;
  int idx0 = ((p0 >> LOG2_PPK) << LOG2_NV) + na.y;
  int idx1 = ((p1 >> LOG2_PPK) << LOG2_NV) + na.w;
  int idx2 = ((p2 >> LOG2_PPK) << LOG2_NV) + nb.y;
  int idx3 = ((p3 >> LOG2_PPK) << LOG2_NV) + nb.w;
  int t0 = T[idx0];                           // all four loads in flight
  int t1 = T[idx1];
  int t2 = T[idx2];
  int t3 = T[idx3];
  if (t0 == p0) T[idx0] = FLAG_FIN | na.x;
  else loser_path(na.y, p0 >> LOG2_PPK, na.x, T2, idx0, use2, ovf_cnt, ovf,
                  S2, ecnt, elist);
  if (t1 == p1) T[idx1] = FLAG_FIN | na.z;
  else loser_path(na.w, p1 >> LOG2_PPK, na.z, T2, idx1, use2, ovf_cnt, ovf,
                  S2, ecnt, elist);
  if (t2 == p2) T[idx2] = FLAG_FIN | nb.x;
  else loser_path(nb.y, p2 >> LOG2_PPK, nb.x, T2, idx2, use2, ovf_cnt, ovf,
                  S2, ecnt, elist);
  if (t3 == p3) T[idx3] = FLAG_FIN | nb.z;
  else loser_path(nb.w, p3 >> LOG2_PPK, nb.z, T2, idx3, use2, ovf_cnt, ovf,
                  S2, ecnt, elist);
}

// ---------------------------------------------------------------------------
// Split-k MFMA gather: block = 4 waves x 16 voxels (same 16 for all waves).
// Wave w owns k in [7w, 7w+kn). Round-0 probes + speculative ovf loads
// issue BEFORE the first barrier (overlap with staging); then T2 probes +
// both rounds' rows, then both MFMA sweeps. Residual overflow (~7/block)
// on the fp32 serial path, dist-1 prefetch.
template <int F16>
__global__ __launch_bounds__(BLOCK, 4) void gather_splitk_kernel(
    const float* __restrict__ in_feature,
    const unsigned short* __restrict__ feat16,
    const float* __restrict__ kernel_w,
    const float* __restrict__ bias,
    const int* __restrict__ T,
    const int* __restrict__ T2, int use2,
    const int* __restrict__ ovf_cnt,
    const int* __restrict__ ovf,
    const unsigned short* __restrict__ Bf,
    float* __restrict__ out, int S2) {
  __shared__ float plane[4][16][PLPAD];       // 9216 B: per-wave partials
  __shared__ int flatE[256];                  // block's overflow entries
  __shared__ int scnt[16];

  const int tid = threadIdx.x;
  const int w = tid >> 6;
  const int lane = tid & 63;
  const int r16 = lane & 15;
  const int quad = lane >> 4;
  const int vb = blockIdx.x << 4;

  // ---- early issue: counts, speculative ovf entries, round-0 probes ----
  const int er = tid & 15;                    // (er, ej): voxel, list pos
  const int ej = tid >> 4;
  int eval = 0;
  if (ej < S2)                                // speculative; masked by scnt
    eval = ovf[(ej << LOG2_NV) + vb + er];
  if (tid < 16) {
    int c = ovf_cnt[vb + tid];
    scnt[tid] = c < S2 ? c : S2;
  }
  const int kb = w * 7;
  const int kn = (w == 3) ? 6 : 7;
  const int v = vb + r16;
  int tv[7];
#pragma unroll
  for (int d = 0; d < 7; ++d)
    tv[d] = (d < kn) ? T[((kb + d) << LOG2_NV) + v] : -1;
  __syncthreads();                            // scnt visible

  // ---- overflow staging: scalar prefix (no priv arrays), flatE write ----
  int myb = 0, tot = 0;
#pragma unroll
  for (int q = 0; q < 16; ++q) {
    int cq = scnt[q];
    if (q < er) myb += cq;
    tot += cq;
  }
  if (ej < scnt[er])
    flatE[myb + ej] = (er << 24) | eval;
  __syncthreads();                            // flatE ready

  // ---- T2 probes + both rounds' rows ----
  int tv2[7];
#pragma unroll
  for (int d = 0; d < 7; ++d)
    tv2[d] = (use2 && d < kn) ? T2[((kb + d) << LOG2_NV) + v] : -1;

  bf16x8 R0[7], R1[7];
#pragma unroll
  for (int d = 0; d < 7; ++d) {
    int t = tv[d];
    int in = (t >= 0) ? (t & 0x3FFFF) : 0;
    bf16x8 a;
    if (F16) {
      a = *reinterpret_cast<const bf16x8*>(feat16 + (in << 5) + (quad << 3));
    } else {
      const float4* ap = (const float4*)(in_feature + (in << 5) + (quad << 3));
      float4 f0 = ap[0], f1 = ap[1];
      a[0] = (short)f2bf(f0.x); a[1] = (short)f2bf(f0.y);
      a[2] = (short)f2bf(f0.z); a[3] = (short)f2bf(f0.w);
      a[4] = (short)f2bf(f1.x); a[5] = (short)f2bf(f1.y);
      a[6] = (short)f2bf(f1.z); a[7] = (short)f2bf(f1.w);
    }
    if (t < 0) a = (bf16x8)0;
    R0[d] = a;
  }
#pragma unroll
  for (int d = 0; d < 7; ++d) {
    int t = tv2[d];
    int in = (t >= 0) ? (t & 0x3FFFF) : 0;
    bf16x8 a;
    if (F16) {
      a = *reinterpret_cast<const bf16x8*>(feat16 + (in << 5) + (quad << 3));
    } else {
      const float4* ap = (const float4*)(in_feature + (in << 5) + (quad << 3));
      float4 f0 = ap[0], f1 = ap[1];
      a[0] = (short)f2bf(f0.x); a[1] = (short)f2bf(f0.y);
      a[2] = (short)f2bf(f0.z); a[3] = (short)f2bf(f0.w);
      a[4] = (short)f2bf(f1.x); a[5] = (short)f2bf(f1.y);
      a[6] = (short)f2bf(f1.z); a[7] = (short)f2bf(f1.w);
    }
    if (t < 0) a = (bf16x8)0;
    R1[d] = a;
  }

  // ---- MFMA sweeps (hi-precision W only) ----
  f32x4 acc0 = {0.f, 0.f, 0.f, 0.f};
  f32x4 acc1 = {0.f, 0.f, 0.f, 0.f};
  const uint4* bfp = (const uint4*)Bf;
#pragma unroll
  for (int d = 0; d < 7; ++d) {
    if (d < kn) {
      int k = kb + d;
      uint4 h0 = bfp[(k * 2 + 0) * 64 + lane];
      uint4 h1 = bfp[(k * 2 + 1) * 64 + lane];
      acc0 = __builtin_amdgcn_mfma_f32_16x16x32_bf16(
          R0[d], *reinterpret_cast<const bf16x8*>(&h0), acc0, 0, 0, 0);
      acc1 = __builtin_amdgcn_mfma_f32_16x16x32_bf16(
          R0[d], *reinterpret_cast<const bf16x8*>(&h1), acc1, 0, 0, 0);
    }
  }
  if (use2) {
#pragma unroll
    for (int d = 0; d < 7; ++d) {
      if (d < kn) {
        int k = kb + d;
        uint4 h0 = bfp[(k * 2 + 0) * 64 + lane];
        uint4 h1 = bfp[(k * 2 + 1) * 64 + lane];
        acc0 = __builtin_amdgcn_mfma_f32_16x16x32_bf16(
            R1[d], *reinterpret_cast<const bf16x8*>(&h0), acc0, 0, 0, 0);
        acc1 = __builtin_amdgcn_mfma_f32_16x16x32_bf16(
            R1[d], *reinterpret_cast<const bf16x8*>(&h1), acc1, 0, 0, 0);
      }
    }
  }

  // ---- dump partials (C/D: col=lane&15, row=quad*4+reg — m89/m91) ----
#pragma unroll
  for (int reg = 0; reg < 4; ++reg) {
    int row = quad * 4 + reg;
    plane[w][row][r16] = acc0[reg];
    plane[w][row][16 + r16] = acc1[reg];
  }

  // ---- residual overflow: entries i = w, w+4, ... ; dist-1 prefetch ----
  const int c32 = lane & 31, h = lane >> 5;
  int i = w;
  int e_cur = 0;
  float4 p0, p1, p2, p3;
  if (i < tot) {
    e_cur = flatE[i];
    const float4* ar =
        (const float4*)(in_feature + ((e_cur & 0x3FFFF) << 5) + (h << 4));
    p0 = ar[0]; p1 = ar[1]; p2 = ar[2]; p3 = ar[3];
  }
  while (i < tot) {
    const int e = e_cur;
    float4 q0 = p0, q1 = p1, q2 = p2, q3 = p3;
    const int inext = i + 4;
    if (inext < tot) {
      e_cur = flatE[inext];
      const float4* ar =
          (const float4*)(in_feature + ((e_cur & 0x3FFFF) << 5) + (h << 4));
      p0 = ar[0]; p1 = ar[1]; p2 = ar[2]; p3 = ar[3];
    }
    const int k2 = (e >> LOG2_NV) & 31;
    const int rr = (e >> 24) & 15;
    const float* wcol = kernel_w + (k2 << 10) + (h << 4) * C_CH + c32;
    float psum = 0.f;
    psum = fmaf(q0.x, wcol[0 * C_CH], psum);
    psum = fmaf(q0.y, wcol[1 * C_CH], psum);
    psum = fmaf(q0.z, wcol[2 * C_CH], psum);
    psum = fmaf(q0.w, wcol[3 * C_CH], psum);
    psum = fmaf(q1.x, wcol[4 * C_CH], psum);
    psum = fmaf(q1.y, wcol[5 * C_CH], psum);
    psum = fmaf(q1.z, wcol[6 * C_CH], psum);
    psum = fmaf(q1.w, wcol[7 * C_CH], psum);
    psum = fmaf(q2.x, wcol[8 * C_CH], psum);
    psum = fmaf(q2.y, wcol[9 * C_CH], psum);
    psum = fmaf(q2.z, wcol[10 * C_CH], psum);
    psum = fmaf(q2.w, wcol[11 * C_CH], psum);
    psum = fmaf(q3.x, wcol[12 * C_CH], psum);
    psum = fmaf(q3.y, wcol[13 * C_CH], psum);
    psum = fmaf(q3.z, wcol[14 * C_CH], psum);
    psum = fmaf(q3.w, wcol[15 * C_CH], psum);
    psum += __shfl_xor(psum, 32);
    if (h == 0) plane[w][rr][c32] += psum;    // own plane: no cross-wave race
    i = inext;
  }

  // ---- merge 4 planes + bias, one float2 store per thread ----
  __syncthreads();
  const int mr = tid >> 4;
  const int mc = (tid & 15) << 1;
  float s0 = plane[0][mr][mc] + plane[1][mr][mc] + plane[2][mr][mc] +
             plane[3][mr][mc] + bias[mc];
  float s1 = plane[0][mr][mc + 1] + plane[1][mr][mc + 1] +
             plane[2][mr][mc + 1] + plane[3][mr][mc + 1] + bias[mc + 1];
  float2 o; o.x = s0; o.y = s1;
  *(float2*)(out + ((vb + mr) << 5) + mc) = o;
}

// ---------------------------------------------------------------------------
// Emergency finisher: the ~tens of entries that overflowed S2.
__global__ __launch_bounds__(BLOCK) void emergency_kernel(
    const float* __restrict__ in_feature, const float* __restrict__ kernel_w,
    const int* __restrict__ ecnt, const int2* __restrict__ elist,
    float* __restrict__ out) {
  int e = blockIdx.x * BLOCK + threadIdx.x;
  int n = *ecnt;
  if (n > ECAP) n = ECAP;
  if (e >= n) return;
  int2 ent = elist[e];
  int v = ent.x, k = ent.y >> LOG2_NV, in = ent.y & 0x3FFFF;
  float a[C_CH];
  const float4* ar = (const float4*)(in_feature + (in << 5));
#pragma unroll
  for (int q = 0; q < 8; ++q) ((float4*)a)[q] = ar[q];
  for (int c = 0; c < C_CH; ++c) {
    float s = 0.f;
#pragma unroll
    for (int i = 0; i < C_CH; ++i)
      s = fmaf(a[i], kernel_w[(k << 10) + i * C_CH + c], s);
    atomicAdd(&out[v * C_CH + c], s);
  }
}

// ---------------------------------------------------------------------------
// Fallback (tiny ws): round-1 direct-atomic version. Correct, slow.
__global__ __launch_bounds__(BLOCK) void init_bias_kernel(
    float* __restrict__ out, const float* __restrict__ bias, int n4) {
  int idx = blockIdx.x * blockDim.x + threadIdx.x;
  if (idx >= n4) return;
  ((float4*)out)[idx] = ((const float4*)bias)[idx & 7];
}

__global__ __launch_bounds__(BLOCK) void scatter_conv_kernel(
    const float* __restrict__ in_feature, const float* __restrict__ kernel_w,
    const int* __restrict__ nbmap, float* __restrict__ out) {
  const int k = blockIdx.x >> 9;
  const int pair = blockIdx.x * BLOCK + threadIdx.x;
  const float* __restrict__ Wk = kernel_w + k * (C_CH * C_CH);
  const int2 nb = ((const int2*)nbmap)[pair];
  const float4* __restrict__ inrow =
      (const float4*)(in_feature + (long)nb.x * C_CH);
  float a[C_CH];
#pragma unroll
  for (int j = 0; j < 8; ++j) ((float4*)a)[j] = inrow[j];
  float acc[C_CH];
#pragma unroll
  for (int c = 0; c < C_CH; ++c) acc[c] = 0.0f;
#pragma unroll
  for (int i = 0; i < C_CH; ++i) {
    const float av = a[i];
#pragma unroll
    for (int c = 0; c < C_CH; ++c)
      acc[c] = fmaf(av, Wk[i * C_CH + c], acc[c]);
  }
  float* __restrict__ orow = out + (long)nb.y * C_CH;
#pragma unroll
  for (int c = 0; c < C_CH; ++c) atomicAdd(orow + c, acc[c]);
}

// ===========================================================================
extern "C" void kernel_launch(void* const* d_in, const int* in_sizes, int n_in,
                              void* d_out, int out_size, void* d_ws,
                              size_t ws_size, hipStream_t stream) {
  const float* in_feature = (const float*)d_in[0];
  const float* kernel_w   = (const float*)d_in[1];
  const float* bias       = (const float*)d_in[2];
  const int*   nbmap      = (const int*)d_in[3];
  float* out = (float*)d_out;
  const int M = in_sizes[3] / 2;                 // 3,538,944
  const int Mq = M / 4;                          // quads of pairs (exact)

  // ws (ints): T[27N] | T2[27N if use2] | ovf_cnt[N] | ecnt[64]
  //            | elist[2*ECAP] | Bf[13824] | ovf[S2*N] | feat16[16N if use16]
  const long FIXED = 64 + 2 * ECAP + 13824;
  long ws_ints = (long)(ws_size / 4);
  long planes = (ws_ints - FIXED) / N_VOX;       // 1 MB planes
  int use2 = 0, use16 = 0;
  long s2c;
  if (planes >= 75) {                            // tier 0: T+T2+feat16+S2>=4
    use2 = 1; use16 = 1;
    s2c = planes - 71;
    if (s2c > 7) s2c = 7;
  } else if (planes >= 59) {                     // tier 1: T+T2+S2>=4
    use2 = 1;
    s2c = planes - 55;
    if (s2c > 7) s2c = 7;
  } else {                                       // tier 2: single T
    s2c = planes - 28;
    if (s2c > 15) s2c = 15;
  }
  int S2 = (int)s2c;

  if (!use2 && S2 < 4) {                         // tier 3: direct atomics
    const int n4 = out_size / 4;
    init_bias_kernel<<<(n4 + BLOCK - 1) / BLOCK, BLOCK, 0, stream>>>(out, bias,
                                                                     n4);
    scatter_conv_kernel<<<M / BLOCK, BLOCK, 0, stream>>>(in_feature, kernel_w,
                                                         nbmap, out);
    return;
  }

  const long TPLANES = (long)K3 * N_VOX;
  int* T        = (int*)d_ws;                       // [27][N_VOX]
  int* T2       = use2 ? (T + TPLANES) : T;         // [27][N_VOX]
  int* ovf_cnt  = T + TPLANES * (1 + use2);         // [N_VOX]
  int* ecnt     = ovf_cnt + N_VOX;                  // [64] (use [0])
  int2* elist   = (int2*)(ecnt + 64);               // [ECAP]
  unsigned short* Bf = (unsigned short*)(ecnt + 64 + 2 * ECAP);  // [27648]
  int* ovf      = ((int*)Bf) + 13824;               // [S2][N_VOX]
  unsigned short* feat16 = (unsigned short*)(ovf + (long)S2 * N_VOX);

  // Single setup kernel: clears + Bf (+feat16).
  const long nt4 = TPLANES * (1 + use2) / 4;        // int4 units
  const long nc4 = (N_VOX + 64) / 4;
  const long total = nt4 + nc4 + (use16 ? (long)NF16 : 0) + FRAGN;
  const long sblocks = (total + BLOCK - 1) / BLOCK;
  setup_kernel<<<(int)sblocks, BLOCK, 0, stream>>>(
      (int4*)T, nt4, (int4*)ovf_cnt, nc4, in_feature, feat16, use16, kernel_w,
      Bf);

  passA_kernel<<<(Mq + BLOCK - 1) / BLOCK, BLOCK, 0, stream>>>(
      (const int4*)nbmap, T, Mq);
  passB_kernel<<<(Mq + BLOCK - 1) / BLOCK, BLOCK, 0, stream>>>(
      (const int4*)nbmap, T, T2, use2, ovf_cnt, ovf, S2, ecnt, elist, Mq);
  if (use16)
    gather_splitk_kernel<1><<<N_VOX / 16, BLOCK, 0, stream>>>(
        in_feature, feat16, kernel_w, bias, T, T2, use2, ovf_cnt, ovf, Bf,
        out, S2);
  else
    gather_splitk_kernel<0><<<N_VOX / 16, BLOCK, 0, stream>>>(
        in_feature, feat16, kernel_w, bias, T, T2, use2, ovf_cnt, ovf, Bf,
        out, S2);
  emergency_kernel<<<ECAP / BLOCK, BLOCK, 0, stream>>>(in_feature, kernel_w,
                                                       ecnt, elist, out);
}

// Round 7
// 361.994 us; speedup vs baseline: 1.0882x; 1.0882x over previous
//
#include <hip/hip_runtime.h>
#include <hip/hip_bf16.h>

// Problem constants (fixed by reference setup_inputs):
//   K3=27, PAIRS_PER_K=131072 (=2^17), N_VOX=262144 (=2^18), C_IN=C_OUT=32
//   M = 3,538,944 pairs. out = [262144][32] fp32.
//
// History: R1 113M fp32 atomics = 5.9ms. R4 MFMA gather 312us. R6/R9:
// runtime-indexed private arrays / forced min-waves -> scratch spill
// (WRITE_SIZE explosion = spill signature). R7 split-k 497us. R8: T2 second
// plane works, but VGPR 108 -> occ 22% flat; one-pass atomic-RETURN claims
// lose to 2-pass; W-lo split numerically no-op. R10 397us: T2 + feat16 at
// 64 VGPR -> gather 154. R11 389us: probes-then-rows -> gather 138. R12
// 394us (noise): setup fusion + 4-pair claim + probe hoist all ~neutral ->
// claim passes are L2/L3 random-line-throughput bound, NOT MLP-bound.
// R13 (this): PACKED T64 word = p[21:0]|in1[39:22]|in2[57:40]|emp[63:58].
//   passA: one plain 8B store (64b aligned stores are single-copy atomic).
//   passB: winner = field-match -> ZERO stores (kills 2.8M random finalize
//     stores); loser CASes in2 field; 2nd loser -> ovf.
//   gather: ONE probe round yields both MFMA rounds (deletes T2 probe round,
//     27MB fetch + one latency trip). ws: 54+1+16+4 = 75 planes (proven).

#define N_VOX    262144
#define LOG2_NV  18
#define C_CH     32
#define K3       27
#define LOG2_PPK 17
#define BLOCK    256
#define FLAG_FIN 0x40000000
#define ECAP     4096
#define PLPAD    36   // plane row stride: rows differ by 36%32=4 -> 2-way max
#define FRAGN    (K3 * 2 * 64)   // uint4 fragments (hi-precision W only)
#define NF16     (N_VOX * 4)     // feat16 uint4 work items

typedef __attribute__((ext_vector_type(8))) short bf16x8;
typedef __attribute__((ext_vector_type(4))) float f32x4;
typedef unsigned long long ull;

#define PMASK   0x3FFFFFull            // p field [21:0]
#define EMPTY2(w) (((w) >> 58) == 0x3Full)

__device__ __forceinline__ unsigned short f2bf(float f) {
  union { __hip_bfloat16 h; unsigned short u; } cv;
  cv.h = __float2bfloat16(f);
  return cv.u;
}

// ---------------------------------------------------------------------------
// Setup: one kernel does all init. Work-id ranges (disjoint memory):
//   [0, nt4)            : clear T/T64 to -1, int4 stores
//   [nt4, nt4+nc4)      : clear ovf_cnt + ecnt to 0
//   [.., +NF16 if use16): feat16 = bf16(in_feature), uint4 stores
//   [.., +FRAGN)        : Bf = W permuted to mfma B-operand lanes (m89/m91)
__global__ __launch_bounds__(BLOCK) void setup_kernel(
    int4* __restrict__ clrT, long nt4, int4* __restrict__ clrC, long nc4,
    const float* __restrict__ in_feature, unsigned short* __restrict__ feat16,
    int use16, const float* __restrict__ kernel_w,
    unsigned short* __restrict__ Bf) {
  long idx = (long)blockIdx.x * BLOCK + threadIdx.x;
  if (idx < nt4) {
    clrT[idx] = make_int4(-1, -1, -1, -1);
    return;
  }
  idx -= nt4;
  if (idx < nc4) {
    clrC[idx] = make_int4(0, 0, 0, 0);
    return;
  }
  idx -= nc4;
  if (use16) {
    if (idx < NF16) {
      const float4* src = (const float4*)in_feature + (idx << 1);
      float4 f0 = src[0], f1 = src[1];
      union { unsigned short u[8]; uint4 v; } pk;
      pk.u[0] = f2bf(f0.x); pk.u[1] = f2bf(f0.y);
      pk.u[2] = f2bf(f0.z); pk.u[3] = f2bf(f0.w);
      pk.u[4] = f2bf(f1.x); pk.u[5] = f2bf(f1.y);
      pk.u[6] = f2bf(f1.z); pk.u[7] = f2bf(f1.w);
      ((uint4*)feat16)[idx] = pk.v;
      return;
    }
    idx -= NF16;
  }
  if (idx < FRAGN) {
    int wid = (int)idx;
    int lane = wid & 63;
    int kc = wid >> 6;
    int k = kc >> 1, t = kc & 1;
    int i0 = (lane >> 4) * 8;
    int c = t * 16 + (lane & 15);
    union { unsigned short u[8]; uint4 v; } pk;
#pragma unroll
    for (int j = 0; j < 8; ++j)
      pk.u[j] = f2bf(kernel_w[(k << 10) + (i0 + j) * C_CH + c]);
    ((uint4*)Bf)[wid] = pk.v;
  }
}

// ---------------------------------------------------------------------------
// PACKED pass A: last-writer-wins claim, one plain 8B store per pair
// (word = p | in<<22 | empty2 marker). 4 pairs/thread.
__global__ __launch_bounds__(BLOCK) void passA_packed(
    const int4* __restrict__ nbmap2, ull* __restrict__ T64, int Mq) {
  int q = blockIdx.x * BLOCK + threadIdx.x;
  if (q >= Mq) return;
  int4 na = nbmap2[q * 2];
  int4 nb = nbmap2[q * 2 + 1];
  int p0 = q << 2, p1 = p0 | 1, p2 = p0 | 2, p3 = p0 | 3;
  const ull EM = 0x3Full << 58;
  T64[((long)(p0 >> LOG2_PPK) << LOG2_NV) + na.y] =
      (ull)p0 | ((ull)na.x << 22) | EM;
  T64[((long)(p1 >> LOG2_PPK) << LOG2_NV) + na.w] =
      (ull)p1 | ((ull)na.z << 22) | EM;
  T64[((long)(p2 >> LOG2_PPK) << LOG2_NV) + nb.y] =
      (ull)p2 | ((ull)nb.x << 22) | EM;
  T64[((long)(p3 >> LOG2_PPK) << LOG2_NV) + nb.w] =
      (ull)p3 | ((ull)nb.z << 22) | EM;
}

// Overflow append (shared by packed/legacy loser paths).
__device__ __forceinline__ void ovf_push(
    int vox, int k, int in, int* __restrict__ ovf_cnt, int* __restrict__ ovf,
    int S2, int* __restrict__ ecnt, int2* __restrict__ elist) {
  int pos = atomicAdd(&ovf_cnt[vox], 1);
  if (pos < S2) {
    ovf[(pos << LOG2_NV) + vox] = (k << LOG2_NV) | in;
  } else {
    int ep = atomicAdd(ecnt, 1);
    if (ep < ECAP) elist[ep] = make_int2(vox, (k << LOG2_NV) | in);
  }
}

// PACKED pass B: winner = p-field match -> NOTHING (zero stores). Loser
// CASes the in2 field (preserves [39:0]); occupied -> ovf. 4 pairs/thread,
// all 4 reads issued before any resolution.
__device__ __forceinline__ void resolve_packed(
    int p, int vox, int in, ull w, ull* __restrict__ T64, long idx,
    int* __restrict__ ovf_cnt, int* __restrict__ ovf, int S2,
    int* __restrict__ ecnt, int2* __restrict__ elist) {
  if ((w & PMASK) == (ull)p) return;          // winner: already in slot 1
  ull cur = w;
  for (;;) {
    if (!EMPTY2(cur)) break;                  // slot 2 taken -> ovf
    ull nw = (cur & ((1ull << 40) - 1)) | ((ull)in << 40);
    ull old = atomicCAS(&T64[idx], cur, nw);
    if (old == cur) return;                   // claimed slot 2
    cur = old;
  }
  ovf_push(vox, p >> LOG2_PPK, in, ovf_cnt, ovf, S2, ecnt, elist);
}

__global__ __launch_bounds__(BLOCK) void passB_packed(
    const int4* __restrict__ nbmap2, ull* __restrict__ T64,
    int* __restrict__ ovf_cnt, int* __restrict__ ovf, int S2,
    int* __restrict__ ecnt, int2* __restrict__ elist, int Mq) {
  int q = blockIdx.x * BLOCK + threadIdx.x;
  if (q >= Mq) return;
  int4 na = nbmap2[q * 2];
  int4 nb = nbmap2[q * 2 + 1];
  int p0 = q << 2, p1 = p0 | 1, p2 = p0 | 2, p3 = p0 | 3;
  long i0 = ((long)(p0 >> LOG2_PPK) << LOG2_NV) + na.y;
  long i1 = ((long)(p1 >> LOG2_PPK) << LOG2_NV) + na.w;
  long i2 = ((long)(p2 >> LOG2_PPK) << LOG2_NV) + nb.y;
  long i3 = ((long)(p3 >> LOG2_PPK) << LOG2_NV) + nb.w;
  ull w0 = T64[i0];                           // all four loads in flight
  ull w1 = T64[i1];
  ull w2 = T64[i2];
  ull w3 = T64[i3];
  resolve_packed(p0, na.y, na.x, w0, T64, i0, ovf_cnt, ovf, S2, ecnt, elist);
  resolve_packed(p1, na.w, na.z, w1, T64, i1, ovf_cnt, ovf, S2, ecnt, elist);
  resolve_packed(p2, nb.y, nb.x, w2, T64, i2, ovf_cnt, ovf, S2, ecnt, elist);
  resolve_packed(p3, nb.w, nb.z, w3, T64, i3, ovf_cnt, ovf, S2, ecnt, elist);
}

// ---------------------------------------------------------------------------
// LEGACY (small-ws insurance): single 4B table, FLAG finalize, no slot 2.
__global__ __launch_bounds__(BLOCK) void passA_legacy(
    const int2* __restrict__ nbmap, int* __restrict__ T, int M) {
  int p = blockIdx.x * BLOCK + threadIdx.x;
  if (p >= M) return;
  int2 nb = nbmap[p];
  T[((p >> LOG2_PPK) << LOG2_NV) + nb.y] = p;
}

__global__ __launch_bounds__(BLOCK) void passB_legacy(
    const int2* __restrict__ nbmap, int* __restrict__ T,
    int* __restrict__ ovf_cnt, int* __restrict__ ovf, int S2,
    int* __restrict__ ecnt, int2* __restrict__ elist, int M) {
  int p = blockIdx.x * BLOCK + threadIdx.x;
  if (p >= M) return;
  int2 nb = nbmap[p];
  int idx = ((p >> LOG2_PPK) << LOG2_NV) + nb.y;
  if (T[idx] == p) {
    T[idx] = FLAG_FIN | nb.x;
  } else {
    ovf_push(nb.y, p >> LOG2_PPK, nb.x, ovf_cnt, ovf, S2, ecnt, elist);
  }
}

// ---------------------------------------------------------------------------
// Split-k MFMA gather: block = 4 waves x 16 voxels (same 16 for all waves).
// Wave w owns k in [7w, 7w+kn). PACKED: ONE probe round (8B word) yields
// both rounds' in-indices; then 14 rows (1 trip) + both MFMA sweeps.
// Residual overflow (~7/block) on the fp32 serial path, dist-1 prefetch.
template <int PACKED, int F16>
__global__ __launch_bounds__(BLOCK, 4) void gather_splitk_kernel(
    const float* __restrict__ in_feature,
    const unsigned short* __restrict__ feat16,
    const float* __restrict__ kernel_w,
    const float* __restrict__ bias,
    const void* __restrict__ Tv,
    const int* __restrict__ ovf_cnt,
    const int* __restrict__ ovf,
    const unsigned short* __restrict__ Bf,
    float* __restrict__ out, int S2) {
  __shared__ float plane[4][16][PLPAD];       // 9216 B: per-wave partials
  __shared__ int flatE[256];                  // block's overflow entries
  __shared__ int scnt[16];

  const int tid = threadIdx.x;
  const int w = tid >> 6;
  const int lane = tid & 63;
  const int r16 = lane & 15;
  const int quad = lane >> 4;
  const int vb = blockIdx.x << 4;

  // ---- early issue: counts, speculative ovf entries, probes ----
  const int er = tid & 15;                    // (er, ej): voxel, list pos
  const int ej = tid >> 4;
  int eval = 0;
  if (ej < S2)                                // speculative; masked by scnt
    eval = ovf[(ej << LOG2_NV) + vb + er];
  if (tid < 16) {
    int c = ovf_cnt[vb + tid];
    scnt[tid] = c < S2 ? c : S2;
  }
  const int kb = w * 7;
  const int kn = (w == 3) ? 6 : 7;
  const int v = vb + r16;

  ull wv[7];
  if (PACKED) {
    const ull* T64 = (const ull*)Tv;
#pragma unroll
    for (int d = 0; d < 7; ++d)
      wv[d] = (d < kn) ? T64[((long)(kb + d) << LOG2_NV) + v] : ~0ull;
  } else {
    const int* T = (const int*)Tv;
#pragma unroll
    for (int d = 0; d < 7; ++d) {
      int t = (d < kn) ? T[((kb + d) << LOG2_NV) + v] : -1;
      // legacy: t = FLAG|in (valid) or -1; map to packed-like: in1 field
      wv[d] = (t >= 0) ? (((ull)(t & 0x3FFFF) << 22) | (0x3Full << 58))
                       : ~0ull;
    }
  }
  __syncthreads();                            // scnt visible

  // ---- overflow staging: scalar prefix (no priv arrays), flatE write ----
  int myb = 0, tot = 0;
#pragma unroll
  for (int q = 0; q < 16; ++q) {
    int cq = scnt[q];
    if (q < er) myb += cq;
    tot += cq;
  }
  if (ej < scnt[er])
    flatE[myb + ej] = (er << 24) | eval;
  __syncthreads();                            // flatE ready

  // ---- rows for both rounds (one trip; invalid -> row0 + zero mask) ----
  bf16x8 R0[7], R1[7];
#pragma unroll
  for (int d = 0; d < 7; ++d) {
    bool val1 = (wv[d] & PMASK) != PMASK;
    int in = val1 ? (int)((wv[d] >> 22) & 0x3FFFF) : 0;
    bf16x8 a;
    if (F16) {
      a = *reinterpret_cast<const bf16x8*>(feat16 + (in << 5) + (quad << 3));
    } else {
      const float4* ap = (const float4*)(in_feature + (in << 5) + (quad << 3));
      float4 f0 = ap[0], f1 = ap[1];
      a[0] = (short)f2bf(f0.x); a[1] = (short)f2bf(f0.y);
      a[2] = (short)f2bf(f0.z); a[3] = (short)f2bf(f0.w);
      a[4] = (short)f2bf(f1.x); a[5] = (short)f2bf(f1.y);
      a[6] = (short)f2bf(f1.z); a[7] = (short)f2bf(f1.w);
    }
    if (!val1) a = (bf16x8)0;
    R0[d] = a;
  }
  if (PACKED) {
#pragma unroll
    for (int d = 0; d < 7; ++d) {
      bool val2 = !EMPTY2(wv[d]);
      int in = val2 ? (int)((wv[d] >> 40) & 0x3FFFF) : 0;
      bf16x8 a;
      if (F16) {
        a = *reinterpret_cast<const bf16x8*>(feat16 + (in << 5) + (quad << 3));
      } else {
        const float4* ap =
            (const float4*)(in_feature + (in << 5) + (quad << 3));
        float4 f0 = ap[0], f1 = ap[1];
        a[0] = (short)f2bf(f0.x); a[1] = (short)f2bf(f0.y);
        a[2] = (short)f2bf(f0.z); a[3] = (short)f2bf(f0.w);
        a[4] = (short)f2bf(f1.x); a[5] = (short)f2bf(f1.y);
        a[6] = (short)f2bf(f1.z); a[7] = (short)f2bf(f1.w);
      }
      if (!val2) a = (bf16x8)0;
      R1[d] = a;
    }
  }

  // ---- MFMA sweeps (hi-precision W only) ----
  f32x4 acc0 = {0.f, 0.f, 0.f, 0.f};
  f32x4 acc1 = {0.f, 0.f, 0.f, 0.f};
  const uint4* bfp = (const uint4*)Bf;
#pragma unroll
  for (int d = 0; d < 7; ++d) {
    if (d < kn) {
      int k = kb + d;
      uint4 h0 = bfp[(k * 2 + 0) * 64 + lane];
      uint4 h1 = bfp[(k * 2 + 1) * 64 + lane];
      acc0 = __builtin_amdgcn_mfma_f32_16x16x32_bf16(
          R0[d], *reinterpret_cast<const bf16x8*>(&h0), acc0, 0, 0, 0);
      acc1 = __builtin_amdgcn_mfma_f32_16x16x32_bf16(
          R0[d], *reinterpret_cast<const bf16x8*>(&h1), acc1, 0, 0, 0);
    }
  }
  if (PACKED) {
#pragma unroll
    for (int d = 0; d < 7; ++d) {
      if (d < kn) {
        int k = kb + d;
        uint4 h0 = bfp[(k * 2 + 0) * 64 + lane];
        uint4 h1 = bfp[(k * 2 + 1) * 64 + lane];
        acc0 = __builtin_amdgcn_mfma_f32_16x16x32_bf16(
            R1[d], *reinterpret_cast<const bf16x8*>(&h0), acc0, 0, 0, 0);
        acc1 = __builtin_amdgcn_mfma_f32_16x16x32_bf16(
            R1[d], *reinterpret_cast<const bf16x8*>(&h1), acc1, 0, 0, 0);
      }
    }
  }

  // ---- dump partials (C/D: col=lane&15, row=quad*4+reg — m89/m91) ----
#pragma unroll
  for (int reg = 0; reg < 4; ++reg) {
    int row = quad * 4 + reg;
    plane[w][row][r16] = acc0[reg];
    plane[w][row][16 + r16] = acc1[reg];
  }

  // ---- residual overflow: entries i = w, w+4, ... ; dist-1 prefetch ----
  const int c32 = lane & 31, h = lane >> 5;
  int i = w;
  int e_cur = 0;
  float4 p0, p1, p2, p3;
  if (i < tot) {
    e_cur = flatE[i];
    const float4* ar =
        (const float4*)(in_feature + ((e_cur & 0x3FFFF) << 5) + (h << 4));
    p0 = ar[0]; p1 = ar[1]; p2 = ar[2]; p3 = ar[3];
  }
  while (i < tot) {
    const int e = e_cur;
    float4 q0 = p0, q1 = p1, q2 = p2, q3 = p3;
    const int inext = i + 4;
    if (inext < tot) {
      e_cur = flatE[inext];
      const float4* ar =
          (const float4*)(in_feature + ((e_cur & 0x3FFFF) << 5) + (h << 4));
      p0 = ar[0]; p1 = ar[1]; p2 = ar[2]; p3 = ar[3];
    }
    const int k2 = (e >> LOG2_NV) & 31;
    const int rr = (e >> 24) & 15;
    const float* wcol = kernel_w + (k2 << 10) + (h << 4) * C_CH + c32;
    float psum = 0.f;
    psum = fmaf(q0.x, wcol[0 * C_CH], psum);
    psum = fmaf(q0.y, wcol[1 * C_CH], psum);
    psum = fmaf(q0.z, wcol[2 * C_CH], psum);
    psum = fmaf(q0.w, wcol[3 * C_CH], psum);
    psum = fmaf(q1.x, wcol[4 * C_CH], psum);
    psum = fmaf(q1.y, wcol[5 * C_CH], psum);
    psum = fmaf(q1.z, wcol[6 * C_CH], psum);
    psum = fmaf(q1.w, wcol[7 * C_CH], psum);
    psum = fmaf(q2.x, wcol[8 * C_CH], psum);
    psum = fmaf(q2.y, wcol[9 * C_CH], psum);
    psum = fmaf(q2.z, wcol[10 * C_CH], psum);
    psum = fmaf(q2.w, wcol[11 * C_CH], psum);
    psum = fmaf(q3.x, wcol[12 * C_CH], psum);
    psum = fmaf(q3.y, wcol[13 * C_CH], psum);
    psum = fmaf(q3.z, wcol[14 * C_CH], psum);
    psum = fmaf(q3.w, wcol[15 * C_CH], psum);
    psum += __shfl_xor(psum, 32);
    if (h == 0) plane[w][rr][c32] += psum;    // own plane: no cross-wave race
    i = inext;
  }

  // ---- merge 4 planes + bias, one float2 store per thread ----
  __syncthreads();
  const int mr = tid >> 4;
  const int mc = (tid & 15) << 1;
  float s0 = plane[0][mr][mc] + plane[1][mr][mc] + plane[2][mr][mc] +
             plane[3][mr][mc] + bias[mc];
  float s1 = plane[0][mr][mc + 1] + plane[1][mr][mc + 1] +
             plane[2][mr][mc + 1] + plane[3][mr][mc + 1] + bias[mc + 1];
  float2 o; o.x = s0; o.y = s1;
  *(float2*)(out + ((vb + mr) << 5) + mc) = o;
}

// ---------------------------------------------------------------------------
// Emergency finisher: the ~tens of entries that overflowed S2.
__global__ __launch_bounds__(BLOCK) void emergency_kernel(
    const float* __restrict__ in_feature, const float* __restrict__ kernel_w,
    const int* __restrict__ ecnt, const int2* __restrict__ elist,
    float* __restrict__ out) {
  int e = blockIdx.x * BLOCK + threadIdx.x;
  int n = *ecnt;
  if (n > ECAP) n = ECAP;
  if (e >= n) return;
  int2 ent = elist[e];
  int v = ent.x, k = ent.y >> LOG2_NV, in = ent.y & 0x3FFFF;
  float a[C_CH];
  const float4* ar = (const float4*)(in_feature + (in << 5));
#pragma unroll
  for (int q = 0; q < 8; ++q) ((float4*)a)[q] = ar[q];
  for (int c = 0; c < C_CH; ++c) {
    float s = 0.f;
#pragma unroll
    for (int i = 0; i < C_CH; ++i)
      s = fmaf(a[i], kernel_w[(k << 10) + i * C_CH + c], s);
    atomicAdd(&out[v * C_CH + c], s);
  }
}

// ---------------------------------------------------------------------------
// Fallback (tiny ws): round-1 direct-atomic version. Correct, slow.
__global__ __launch_bounds__(BLOCK) void init_bias_kernel(
    float* __restrict__ out, const float* __restrict__ bias, int n4) {
  int idx = blockIdx.x * blockDim.x + threadIdx.x;
  if (idx >= n4) return;
  ((float4*)out)[idx] = ((const float4*)bias)[idx & 7];
}

__global__ __launch_bounds__(BLOCK) void scatter_conv_kernel(
    const float* __restrict__ in_feature, const float* __restrict__ kernel_w,
    const int* __restrict__ nbmap, float* __restrict__ out) {
  const int k = blockIdx.x >> 9;
  const int pair = blockIdx.x * BLOCK + threadIdx.x;
  const float* __restrict__ Wk = kernel_w + k * (C_CH * C_CH);
  const int2 nb = ((const int2*)nbmap)[pair];
  const float4* __restrict__ inrow =
      (const float4*)(in_feature + (long)nb.x * C_CH);
  float a[C_CH];
#pragma unroll
  for (int j = 0; j < 8; ++j) ((float4*)a)[j] = inrow[j];
  float acc[C_CH];
#pragma unroll
  for (int c = 0; c < C_CH; ++c) acc[c] = 0.0f;
#pragma unroll
  for (int i = 0; i < C_CH; ++i) {
    const float av = a[i];
#pragma unroll
    for (int c = 0; c < C_CH; ++c)
      acc[c] = fmaf(av, Wk[i * C_CH + c], acc[c]);
  }
  float* __restrict__ orow = out + (long)nb.y * C_CH;
#pragma unroll
  for (int c = 0; c < C_CH; ++c) atomicAdd(orow + c, acc[c]);
}

// ===========================================================================
extern "C" void kernel_launch(void* const* d_in, const int* in_sizes, int n_in,
                              void* d_out, int out_size, void* d_ws,
                              size_t ws_size, hipStream_t stream) {
  const float* in_feature = (const float*)d_in[0];
  const float* kernel_w   = (const float*)d_in[1];
  const float* bias       = (const float*)d_in[2];
  const int*   nbmap      = (const int*)d_in[3];
  float* out = (float*)d_out;
  const int M = in_sizes[3] / 2;                 // 3,538,944
  const int Mq = M / 4;                          // quads of pairs (exact)

  // ws (ints): T64[54N] (packed) or T[27N] (legacy) | ovf_cnt[N] | ecnt[64]
  //            | elist[2*ECAP] | Bf[13824] | ovf[S2*N] | feat16[16N if use16]
  const long FIXED = 64 + 2 * ECAP + 13824;
  long ws_ints = (long)(ws_size / 4);
  long planes = (ws_ints - FIXED) / N_VOX;       // 1 MB planes
  int packed = 0, use16 = 0;
  long s2c;
  if (planes >= 75) {                            // tier 0: T64+feat16+S2>=4
    packed = 1; use16 = 1;
    s2c = planes - 71;
    if (s2c > 7) s2c = 7;
  } else if (planes >= 59) {                     // tier 1: T64, f32 rows
    packed = 1;
    s2c = planes - 55;
    if (s2c > 7) s2c = 7;
  } else {                                       // tier 2: legacy single T
    s2c = planes - 28;
    if (s2c > 15) s2c = 15;
  }
  int S2 = (int)s2c;

  if (!packed && S2 < 4) {                       // tier 3: direct atomics
    const int n4 = out_size / 4;
    init_bias_kernel<<<(n4 + BLOCK - 1) / BLOCK, BLOCK, 0, stream>>>(out, bias,
                                                                     n4);
    scatter_conv_kernel<<<M / BLOCK, BLOCK, 0, stream>>>(in_feature, kernel_w,
                                                         nbmap, out);
    return;
  }

  const long planesT = packed ? 2L * K3 : (long)K3;   // in 1MB int-planes
  int* Tbase    = (int*)d_ws;                       // T64 or T
  int* ovf_cnt  = Tbase + planesT * N_VOX;          // [N_VOX]
  int* ecnt     = ovf_cnt + N_VOX;                  // [64] (use [0])
  int2* elist   = (int2*)(ecnt + 64);               // [ECAP]
  unsigned short* Bf = (unsigned short*)(ecnt + 64 + 2 * ECAP);  // [27648]
  int* ovf      = ((int*)Bf) + 13824;               // [S2][N_VOX]
  unsigned short* feat16 = (unsigned short*)(ovf + (long)S2 * N_VOX);

  // Single setup kernel: clears + Bf (+feat16).
  const long nt4 = planesT * N_VOX / 4;             // int4 units
  const long nc4 = (N_VOX + 64) / 4;
  const long total = nt4 + nc4 + (use16 ? (long)NF16 : 0) + FRAGN;
  const long sblocks = (total + BLOCK - 1) / BLOCK;
  setup_kernel<<<(int)sblocks, BLOCK, 0, stream>>>(
      (int4*)Tbase, nt4, (int4*)ovf_cnt, nc4, in_feature, feat16, use16,
      kernel_w, Bf);

  if (packed) {
    passA_packed<<<(Mq + BLOCK - 1) / BLOCK, BLOCK, 0, stream>>>(
        (const int4*)nbmap, (ull*)Tbase, Mq);
    passB_packed<<<(Mq + BLOCK - 1) / BLOCK, BLOCK, 0, stream>>>(
        (const int4*)nbmap, (ull*)Tbase, ovf_cnt, ovf, S2, ecnt, elist, Mq);
    if (use16)
      gather_splitk_kernel<1, 1><<<N_VOX / 16, BLOCK, 0, stream>>>(
          in_feature, feat16, kernel_w, bias, (const void*)Tbase, ovf_cnt,
          ovf, Bf, out, S2);
    else
      gather_splitk_kernel<1, 0><<<N_VOX / 16, BLOCK, 0, stream>>>(
          in_feature, feat16, kernel_w, bias, (const void*)Tbase, ovf_cnt,
          ovf, Bf, out, S2);
  } else {
    passA_legacy<<<(M + BLOCK - 1) / BLOCK, BLOCK, 0, stream>>>(
        (const int2*)nbmap, Tbase, M);
    passB_legacy<<<(M + BLOCK - 1) / BLOCK, BLOCK, 0, stream>>>(
        (const int2*)nbmap, Tbase, ovf_cnt, ovf, S2, ecnt, elist, M);
    gather_splitk_kernel<0, 0><<<N_VOX / 16, BLOCK, 0, stream>>>(
        in_feature, feat16, kernel_w, bias, (const void*)Tbase, ovf_cnt, ovf,
        Bf, out, S2);
  }
  emergency_kernel<<<ECAP / BLOCK, BLOCK, 0, stream>>>(in_feature, kernel_w,
                                                       ecnt, elist, out);
}